// Round 27
// baseline (202.114 us; speedup 1.0000x reference)
//
#include <hip/hip_runtime.h>
#include <math.h>

// TGCN: bf16 feature-space GCN aggregation (fp32 accum, uint2 gathers) ->
// fused GRU (merged Z+R, hq in-place, 4 waves, 32-ROW tiles: 1563 blocks ->
// 6.1 blocks/CU, 2x resident waves vs 64-row). CSR via ZERO global atomics.
// NEC=32. front: 1024 threads. 8 dispatches.

#define HD 128
#define RBITS 13
#define RSIZE 8192          // nodes per histogram/fill range
#define POOLB 512           // pool partial blocks

typedef __attribute__((ext_vector_type(8))) short short8;
typedef __attribute__((ext_vector_type(4))) float f32x4;

__device__ __forceinline__ ushort f2bf(float f) {
    union { float f; unsigned u; } v; v.f = f;
    unsigned r = (v.u + 0x7FFFu + ((v.u >> 16) & 1u)) >> 16;
    return (ushort)r;
}
__device__ __forceinline__ float bf2f(ushort h) {
    union { unsigned u; float f; } v; v.u = ((unsigned)h) << 16;
    return v.f;
}
__device__ __forceinline__ float bflo(unsigned u) {
    union { unsigned u; float f; } v; v.u = u << 16; return v.f;
}
__device__ __forceinline__ float bfhi(unsigned u) {
    union { unsigned u; float f; } v; v.u = u & 0xFFFF0000u; return v.f;
}
__device__ __forceinline__ float fast_sigmoid(float x) {
    return 1.0f / (1.0f + __expf(-x));
}
__device__ __forceinline__ float fast_tanh(float x) {
    float e = __expf(-2.0f * fabsf(x));
    float m = (1.0f - e) / (1.0f + e);
    return copysignf(m, x);
}

// FRONT: block-partitioned fat kernel, 1024 threads.
__global__ __launch_bounds__(1024) void front_kernel(
        const int* __restrict__ dst, const float* __restrict__ w,
        int* __restrict__ pc, float* __restrict__ pw,
        int NPAD, int NR, int EC, int E, int NHIST,
        const float* __restrict__ nf, const float* __restrict__ h0,
        ushort* __restrict__ nfb, ushort* __restrict__ h0b, int n, int NPREP,
        const float* __restrict__ Wz, const float* __restrict__ Wr,
        const float* __restrict__ Wh,
        const float* __restrict__ lzW, const float* __restrict__ lrW,
        const float* __restrict__ lhW,
        const float* __restrict__ bz, const float* __restrict__ br,
        const float* __restrict__ bh,
        const float* __restrict__ lzb, const float* __restrict__ lrb,
        const float* __restrict__ lhb,
        ushort* __restrict__ BT, float* __restrict__ lb2) {
    __shared__ int lc[RSIZE];
    __shared__ float lw[RSIZE];
    int b = blockIdx.x;
    int t = threadIdx.x;
    if (b < NHIST) {
        int r = b % NR;
        int c = b / NR;
        for (int k = t; k < RSIZE; k += 1024) { lc[k] = 0; lw[k] = 0.0f; }
        __syncthreads();
        int base = c * EC;              // EC multiple of 4 -> 16B aligned
        int end = min(base + EC, E);
        int rbase = r << RBITS;
        for (int eb = base + t * 4; eb < end; eb += 4096) {
            if (eb + 3 < end) {
                int4 d4 = *(const int4*)(dst + eb);
                if ((d4.x >> RBITS) == r) {
                    int dl = d4.x - rbase;
                    atomicAdd(&lc[dl], 1); atomicAdd(&lw[dl], w[eb]);
                }
                if ((d4.y >> RBITS) == r) {
                    int dl = d4.y - rbase;
                    atomicAdd(&lc[dl], 1); atomicAdd(&lw[dl], w[eb + 1]);
                }
                if ((d4.z >> RBITS) == r) {
                    int dl = d4.z - rbase;
                    atomicAdd(&lc[dl], 1); atomicAdd(&lw[dl], w[eb + 2]);
                }
                if ((d4.w >> RBITS) == r) {
                    int dl = d4.w - rbase;
                    atomicAdd(&lc[dl], 1); atomicAdd(&lw[dl], w[eb + 3]);
                }
            } else {
                for (int u = 0; u < 4; ++u) {
                    int e = eb + u;
                    if (e < end) {
                        int d = dst[e];
                        if ((d >> RBITS) == r) {
                            int dl = d - rbase;
                            atomicAdd(&lc[dl], 1); atomicAdd(&lw[dl], w[e]);
                        }
                    }
                }
            }
        }
        __syncthreads();
        size_t o = (size_t)c * NPAD + (r << RBITS);
        for (int k = t; k < RSIZE; k += 1024) {
            pc[o + k] = lc[k];
            pw[o + k] = lw[k];
        }
    } else if (b < NHIST + NPREP) {
        int idx = (b - NHIST) * 1024 + t;
        int total8 = n * (HD / 8);
        if (idx < total8) {
            const float4* p = (const float4*)(nf + (size_t)idx * 8);
            float4 x = p[0], y = p[1];
            short8 o;
            o[0] = (short)f2bf(x.x); o[1] = (short)f2bf(x.y);
            o[2] = (short)f2bf(x.z); o[3] = (short)f2bf(x.w);
            o[4] = (short)f2bf(y.x); o[5] = (short)f2bf(y.y);
            o[6] = (short)f2bf(y.z); o[7] = (short)f2bf(y.w);
            *(short8*)(nfb + (size_t)idx * 8) = o;
            const float4* q = (const float4*)(h0 + (size_t)idx * 8);
            float4 a = q[0], bq = q[1];
            short8 o2;
            o2[0] = (short)f2bf(a.x); o2[1] = (short)f2bf(a.y);
            o2[2] = (short)f2bf(a.z); o2[3] = (short)f2bf(a.w);
            o2[4] = (short)f2bf(bq.x); o2[5] = (short)f2bf(bq.y);
            o2[6] = (short)f2bf(bq.z); o2[7] = (short)f2bf(bq.w);
            *(short8*)(h0b + (size_t)idx * 8) = o2;
        }
    } else if (b < NHIST + NPREP + 96) {
        if (t < 256) {
            int f = b - NHIST - NPREP;
            int g = f >> 5, kt = f & 31;
            const float* W  = (g == 0) ? Wz  : (g == 1) ? Wr  : Wh;
            const float* lW = (g == 0) ? lzW : (g == 1) ? lrW : lhW;
            int j = t & 127, kh = t >> 7;
            int k0 = kt * 4 + kh * 2;
            float m0 = 0.f, m1 = 0.f;
            for (int mm = 0; mm < 128; ++mm) {
                float lv = lW[mm * 128 + j];
                m0 += W[(k0 + 0) * 128 + mm] * lv;
                m1 += W[(k0 + 1) * 128 + mm] * lv;
            }
            ushort* dstc = BT + ((size_t)g * 128 + j) * 256;
            dstc[k0 + 0] = f2bf(m0);
            dstc[k0 + 1] = f2bf(m1);
#pragma unroll
            for (int u = 0; u < 2; ++u) {
                int mm = k0 + u;
                dstc[128 + mm] = f2bf(lW[(128 + mm) * 128 + j]);
            }
        }
    } else {
        int g = b - NHIST - NPREP - 96;
        if (t < 128) {
            const float* lW = (g == 0) ? lzW : (g == 1) ? lrW : lhW;
            const float* bg = (g == 0) ? bz  : (g == 1) ? br  : bh;
            const float* lb = (g == 0) ? lzb : (g == 1) ? lrb : lhb;
            int j = t;
            float s = lb[j];
            for (int mm = 0; mm < 128; ++mm) s += bg[mm] * lW[mm * 128 + j];
            lb2[g * 128 + j] = s;
        }
    }
}

// reduce_hist + scan_partial
__global__ __launch_bounds__(256) void reduce_scanpart_kernel(
        const int* __restrict__ pc, const float* __restrict__ pw,
        int* __restrict__ counts, float* __restrict__ dinv,
        int* __restrict__ bsums, int NPAD, int NEC, int N) {
    __shared__ int ws[4];
    int b = blockIdx.x, t = threadIdx.x;
    int i = b * 1024 + t * 4;
    int c0 = 0, c1 = 0, c2 = 0, c3 = 0;
    float d0 = 1.f, d1 = 1.f, d2 = 1.f, d3 = 1.f;
    for (int c = 0; c < NEC; ++c) {
        size_t base = (size_t)c * NPAD + i;
        int4 pcv = *(const int4*)(pc + base);
        float4 pwv = *(const float4*)(pw + base);
        c0 += pcv.x; c1 += pcv.y; c2 += pcv.z; c3 += pcv.w;
        d0 += pwv.x; d1 += pwv.y; d2 += pwv.z; d3 += pwv.w;
    }
    if (i + 3 < N) {
        int4 cv; cv.x = c0; cv.y = c1; cv.z = c2; cv.w = c3;
        *(int4*)(counts + i) = cv;
        float4 dv;
        dv.x = rsqrtf(d0); dv.y = rsqrtf(d1);
        dv.z = rsqrtf(d2); dv.w = rsqrtf(d3);
        *(float4*)(dinv + i) = dv;
    } else {
        if (i < N)     { counts[i] = c0;     dinv[i] = rsqrtf(d0); }
        if (i + 1 < N) { counts[i + 1] = c1; dinv[i + 1] = rsqrtf(d1); }
        if (i + 2 < N) { counts[i + 2] = c2; dinv[i + 2] = rsqrtf(d2); }
        if (i + 3 < N) { counts[i + 3] = c3; dinv[i + 3] = rsqrtf(d3); }
    }
    int s = 0;
    if (i < N) s += c0;
    if (i + 1 < N) s += c1;
    if (i + 2 < N) s += c2;
    if (i + 3 < N) s += c3;
    for (int off = 1; off < 64; off <<= 1) s += __shfl_xor(s, off, 64);
    if ((t & 63) == 0) ws[t >> 6] = s;
    __syncthreads();
    if (t == 0) bsums[b] = ws[0] + ws[1] + ws[2] + ws[3];
}

// scan_bsums + scan_final + col_scan
__global__ __launch_bounds__(256) void scanfinal_colscan_kernel(
        const int* __restrict__ counts, const int* __restrict__ bsums,
        int* __restrict__ row_ptr, int* __restrict__ pc,
        int NPAD, int NEC, int NB, int n) {
    __shared__ int ws[4];
    __shared__ int sb[64];
    __shared__ int stot;
    int b = blockIdx.x, t = threadIdx.x;
    if (t < 64) {
        int v = (t < NB) ? bsums[t] : 0;
        int x = v;
        for (int off = 1; off < 64; off <<= 1) {
            int y = __shfl_up(x, off, 64);
            if (t >= off) x += y;
        }
        sb[t] = x - v;
        if (t == NB - 1) stot = x;
    }
    __syncthreads();
    int base = sb[b];
    int idx = b * 1024 + t * 4;
    int4 v = {0, 0, 0, 0};
    if (idx + 3 < n) v = *(const int4*)(counts + idx);
    else {
        if (idx < n) v.x = counts[idx];
        if (idx + 1 < n) v.y = counts[idx + 1];
        if (idx + 2 < n) v.z = counts[idx + 2];
        if (idx + 3 < n) v.w = counts[idx + 3];
    }
    int s = v.x + v.y + v.z + v.w;
    int lane = t & 63, wid = t >> 6;
    int x = s;
    for (int off = 1; off < 64; off <<= 1) {
        int y = __shfl_up(x, off, 64);
        if (lane >= off) x += y;
    }
    if (lane == 63) ws[wid] = x;
    __syncthreads();
    int woff = 0;
    for (int wv = 0; wv < wid; ++wv) woff += ws[wv];
    int run = base + woff + x - s;
    int4 rp;
    rp.x = run; rp.y = run + v.x; rp.z = rp.y + v.y; rp.w = rp.z + v.z;
    if (idx + 3 < n) {
        *(int4*)(row_ptr + idx) = rp;
    } else {
        if (idx < n) row_ptr[idx] = rp.x;
        if (idx + 1 < n) row_ptr[idx + 1] = rp.y;
        if (idx + 2 < n) row_ptr[idx + 2] = rp.z;
        if (idx + 3 < n) row_ptr[idx + 3] = rp.w;
    }
    if (b == 0 && t == 0) row_ptr[n] = stot;
    int4 run4 = rp;
    for (int c = 0; c < NEC; ++c) {
        size_t ba = (size_t)c * NPAD + idx;
        int4 pv = *(const int4*)(pc + ba);
        *(int4*)(pc + ba) = run4;
        run4.x += pv.x; run4.y += pv.y; run4.z += pv.z; run4.w += pv.w;
    }
}

// fill: block (c,r); pco range-slice preloaded into LDS; packed ushort ranks;
// 1024 threads.
__global__ __launch_bounds__(1024) void fill2d_kernel(
        const int* __restrict__ src, const int* __restrict__ dst,
        const float* __restrict__ w, const float* __restrict__ dinv,
        const int* __restrict__ pc, int2* __restrict__ es,
        int NPAD, int NR, int EC, int E) {
    __shared__ int po[RSIZE];
    __shared__ unsigned pk[RSIZE / 2];
    int r = blockIdx.x % NR;
    int c = blockIdx.x / NR;
    int t = threadIdx.x;
    const int* __restrict__ pco = pc + (size_t)c * NPAD + (r << RBITS);
    for (int b = t; b < RSIZE / 2; b += 1024) pk[b] = 0u;
    for (int b = t; b < RSIZE; b += 1024) po[b] = pco[b];
    __syncthreads();
    int base = c * EC;
    int end = min(base + EC, E);
    int rbase = r << RBITS;
    for (int e = base + t; e < end; e += 1024) {
        int d = dst[e];
        if ((d >> RBITS) == r) {
            int dl = d - rbase;
            unsigned sh = (dl & 1) * 16;
            unsigned old = atomicAdd(&pk[dl >> 1], 1u << sh);
            int rank = (int)((old >> sh) & 0xFFFFu);
            int pos = po[dl] + rank;
            int s = src[e];
            float nv = dinv[s] * w[e];
            int2 ev;
            ev.x = s;
            ev.y = __float_as_int(nv);
            es[pos] = ev;
        }
    }
}

// agg: ONE node per wave; half-waves take alternating 8-edge batches; uint2.
__global__ __launch_bounds__(256) void agg_feat_kernel(
        const uint2* __restrict__ nfb2, const float* __restrict__ dinv,
        const int* __restrict__ row_ptr, const int2* __restrict__ es,
        uint2* __restrict__ aggb2, int n) {
    int lane = threadIdx.x & 63;
    int wv = threadIdx.x >> 6;
    int i = blockIdx.x * 4 + wv;
    if (i >= n) return;
    int sub = lane & 31;
    int half = lane >> 5;
    float dA = dinv[i];
    float a0 = 0.f, a1 = 0.f, a2 = 0.f, a3 = 0.f;
    int e0 = row_ptr[i], e1 = row_ptr[i + 1];
    int iters = (e1 - e0 + 15) >> 4;

    int2 zed; zed.x = 0; zed.y = 0;
    int e = e0 + half * 8;
    int2 buf[8];
#pragma unroll
    for (int u = 0; u < 8; ++u) {
        int ee = e + u;
        buf[u] = (ee < e1) ? es[ee] : zed;
    }
    for (int it = 0; it < iters; ++it) {
        uint2 v[8]; float w[8];
#pragma unroll
        for (int u = 0; u < 8; ++u) {
            v[u] = nfb2[(size_t)buf[u].x * 32 + sub];
            w[u] = __int_as_float(buf[u].y);
        }
        int en = e + 16;
#pragma unroll
        for (int u = 0; u < 8; ++u) {
            int ee = en + u;
            buf[u] = (it + 1 < iters && ee < e1) ? es[ee] : zed;
        }
#pragma unroll
        for (int u = 0; u < 8; ++u) {
            a0 += w[u] * bflo(v[u].x);
            a1 += w[u] * bfhi(v[u].x);
            a2 += w[u] * bflo(v[u].y);
            a3 += w[u] * bfhi(v[u].y);
        }
        e = en;
    }
    a0 += __shfl_xor(a0, 32, 64);
    a1 += __shfl_xor(a1, 32, 64);
    a2 += __shfl_xor(a2, 32, 64);
    a3 += __shfl_xor(a3, 32, 64);
    if (half == 0) {
        uint2 self = nfb2[(size_t)i * 32 + sub];
        float f0 = dA * (dA * bflo(self.x) + a0);
        float f1 = dA * (dA * bfhi(self.x) + a1);
        float f2 = dA * (dA * bflo(self.y) + a2);
        float f3 = dA * (dA * bfhi(self.y) + a3);
        uint2 o;
        o.x = (unsigned)f2bf(f0) | ((unsigned)f2bf(f1) << 16);
        o.y = (unsigned)f2bf(f2) | ((unsigned)f2bf(f3) << 16);
        aggb2[(size_t)i * 32 + sub] = o;
    }
}

// Fused GRU: 32-ROW tile, 4 waves (each wave 32 cols x 32 rows, rf=2),
// merged Z+R, hq in-place over Ah0, bf16 h0b staging, depth-1 B prefetch.
// 1563 blocks -> 6.1 blocks/CU (2x waves/SIMD vs 64-row tiles).
#define BADDR(g, cf, ks) (BT + (size_t)((g) * 128 + c0 + (cf) * 16 + rlo) * 256 \
                          + (ks) * 32 + koff)
__global__ __launch_bounds__(256) void gru_fused_kernel(
        const ushort* __restrict__ aggb, const ushort* __restrict__ h0b,
        const ushort* __restrict__ BT, const float* __restrict__ lb2,
        float* __restrict__ hout, int n) {
    __shared__ ushort Aag[32][136];
    __shared__ ushort Ah0[32][136];
    int t = threadIdx.x;
    int i0 = blockIdx.x * 32;

    int w = t >> 6, lane = t & 63;
    int rlo = lane & 15, koff = (lane >> 4) * 8, rbase = (lane >> 4) * 4;
    int c0 = w * 32;

    short8 bz0 = *(const short8*)BADDR(0, 0, 0);
    short8 bz1 = *(const short8*)BADDR(0, 1, 0);
    short8 br0 = *(const short8*)BADDR(1, 0, 0);
    short8 br1 = *(const short8*)BADDR(1, 1, 0);

    for (int c = t; c < 512; c += 256) {
        int row = c >> 4, c8 = c & 15;
        size_t gp = (size_t)(i0 + row) * HD + c8 * 8;
        *(short8*)&Aag[row][c8 * 8] = *(const short8*)(aggb + gp);
        *(short8*)&Ah0[row][c8 * 8] = *(const short8*)(h0b + gp);
    }
    __syncthreads();

    const f32x4 zero4 = {0.f, 0.f, 0.f, 0.f};
    f32x4 accz[2][2], accr[2][2];
#pragma unroll
    for (int rf = 0; rf < 2; ++rf) {
        accz[rf][0] = zero4; accz[rf][1] = zero4;
        accr[rf][0] = zero4; accr[rf][1] = zero4;
    }

#pragma unroll
    for (int ks = 0; ks < 8; ++ks) {
        short8 nz0, nz1, nr0, nr1;
        if (ks < 7) {
            nz0 = *(const short8*)BADDR(0, 0, ks + 1);
            nz1 = *(const short8*)BADDR(0, 1, ks + 1);
            nr0 = *(const short8*)BADDR(1, 0, ks + 1);
            nr1 = *(const short8*)BADDR(1, 1, ks + 1);
        }
#pragma unroll
        for (int rf = 0; rf < 2; ++rf) {
            short8 af = (ks < 4)
                ? *(const short8*)&Aag[rf * 16 + rlo][ks * 32 + koff]
                : *(const short8*)&Ah0[rf * 16 + rlo][(ks - 4) * 32 + koff];
            accz[rf][0] = __builtin_amdgcn_mfma_f32_16x16x32_bf16(af, bz0, accz[rf][0], 0, 0, 0);
            accz[rf][1] = __builtin_amdgcn_mfma_f32_16x16x32_bf16(af, bz1, accz[rf][1], 0, 0, 0);
            accr[rf][0] = __builtin_amdgcn_mfma_f32_16x16x32_bf16(af, br0, accr[rf][0], 0, 0, 0);
            accr[rf][1] = __builtin_amdgcn_mfma_f32_16x16x32_bf16(af, br1, accr[rf][1], 0, 0, 0);
        }
        if (ks < 7) { bz0 = nz0; bz1 = nz1; br0 = nr0; br1 = nr1; }
    }

    float zv[2][2][4], hv[2][2][4];
#pragma unroll
    for (int rf = 0; rf < 2; ++rf)
#pragma unroll
        for (int cf = 0; cf < 2; ++cf) {
            int lc = c0 + cf * 16 + rlo;
            float bvz = lb2[lc];
#pragma unroll
            for (int i = 0; i < 4; ++i) {
                int row = rf * 16 + rbase + i;
                zv[rf][cf][i] = fast_sigmoid(accz[rf][cf][i] + bvz);
                hv[rf][cf][i] = bf2f(Ah0[row][lc]);
            }
        }
    __syncthreads();

#pragma unroll
    for (int rf = 0; rf < 2; ++rf)
#pragma unroll
        for (int cf = 0; cf < 2; ++cf) {
            int lc = c0 + cf * 16 + rlo;
            float bvr = lb2[128 + lc];
#pragma unroll
            for (int i = 0; i < 4; ++i) {
                int row = rf * 16 + rbase + i;
                float r = fast_sigmoid(accr[rf][cf][i] + bvr);
                Ah0[row][lc] = f2bf(r * hv[rf][cf][i]);
            }
        }
    short8 bh0 = *(const short8*)BADDR(2, 0, 0);
    short8 bh1 = *(const short8*)BADDR(2, 1, 0);
    __syncthreads();

    f32x4 acch[2][2];
#pragma unroll
    for (int rf = 0; rf < 2; ++rf) { acch[rf][0] = zero4; acch[rf][1] = zero4; }
#pragma unroll
    for (int ks = 0; ks < 8; ++ks) {
        short8 nh0, nh1;
        if (ks < 7) {
            nh0 = *(const short8*)BADDR(2, 0, ks + 1);
            nh1 = *(const short8*)BADDR(2, 1, ks + 1);
        }
#pragma unroll
        for (int rf = 0; rf < 2; ++rf) {
            short8 af = (ks < 4)
                ? *(const short8*)&Aag[rf * 16 + rlo][ks * 32 + koff]
                : *(const short8*)&Ah0[rf * 16 + rlo][(ks - 4) * 32 + koff];
            acch[rf][0] = __builtin_amdgcn_mfma_f32_16x16x32_bf16(af, bh0, acch[rf][0], 0, 0, 0);
            acch[rf][1] = __builtin_amdgcn_mfma_f32_16x16x32_bf16(af, bh1, acch[rf][1], 0, 0, 0);
        }
        if (ks < 7) { bh0 = nh0; bh1 = nh1; }
    }
#pragma unroll
    for (int rf = 0; rf < 2; ++rf)
#pragma unroll
        for (int cf = 0; cf < 2; ++cf) {
            int lc = c0 + cf * 16 + rlo;
            float bv = lb2[256 + lc];
#pragma unroll
            for (int i = 0; i < 4; ++i) {
                int row = rf * 16 + rbase + i;
                int grow = i0 + row;
                if (grow < n) {
                    float ht = fast_tanh(acch[rf][cf][i] + bv);
                    float z = zv[rf][cf][i];
                    hout[(size_t)grow * HD + lc] = z * hv[rf][cf][i] + (1.0f - z) * ht;
                }
            }
        }
}

// pool: per-block partials, NO atomics.
__global__ __launch_bounds__(128) void pool_partial_kernel(
        const float* __restrict__ hout, const int* __restrict__ nids,
        float* __restrict__ partials, int U) {
    int t = threadIdx.x;
    float pa = 0.0f;
    for (int u = blockIdx.x; u < U; u += gridDim.x) {
        int nid = nids[u];
        pa += fmaxf(hout[(size_t)nid * HD + t], 0.0f);
    }
    partials[(size_t)blockIdx.x * HD + t] = pa;
}

__global__ __launch_bounds__(128) void decoder_kernel(
        const float* __restrict__ partials, float invU,
        const float* __restrict__ linW, const float* __restrict__ linb,
        const float* __restrict__ dnW, const float* __restrict__ dnb,
        const float* __restrict__ outW, const float* __restrict__ outb,
        float* pred, int C) {
    __shared__ float sh[HD];
    int t = threadIdx.x;
    float s = 0.0f;
    for (int b = 0; b < POOLB; ++b) s += partials[(size_t)b * HD + t];
    sh[t] = s * invU;
    __syncthreads();
    float v = linb[t];
    for (int k = 0; k < HD; ++k) v += sh[k] * linW[k * HD + t];
    __syncthreads();
    sh[t] = v;
    __syncthreads();
    float d = dnb[t];
    for (int k = 0; k < HD; ++k) d += sh[k] * dnW[k * HD + t];
    d = fmaxf(d, 0.0f);
    __syncthreads();
    sh[t] = d;
    __syncthreads();
    if (t < C) {
        float p = outb[t];
        for (int k = 0; k < HD; ++k) p += sh[k] * outW[k * C + t];
        pred[t] = 1.0f / (1.0f + expf(-p));
    }
}

extern "C" void kernel_launch(void* const* d_in, const int* in_sizes, int n_in,
                              void* d_out, int out_size, void* d_ws, size_t ws_size,
                              hipStream_t stream) {
    const float* node_feat = (const float*)d_in[0];
    const float* edge_w    = (const float*)d_in[1];
    const float* h0        = (const float*)d_in[2];
    const float* Wz  = (const float*)d_in[3];  const float* bz  = (const float*)d_in[4];
    const float* Wr  = (const float*)d_in[5];  const float* br  = (const float*)d_in[6];
    const float* Wh  = (const float*)d_in[7];  const float* bh  = (const float*)d_in[8];
    const float* lzW = (const float*)d_in[9];  const float* lzb = (const float*)d_in[10];
    const float* lrW = (const float*)d_in[11]; const float* lrb = (const float*)d_in[12];
    const float* lhW = (const float*)d_in[13]; const float* lhb = (const float*)d_in[14];
    const float* linW= (const float*)d_in[15]; const float* linb= (const float*)d_in[16];
    const float* dnW = (const float*)d_in[17]; const float* dnb = (const float*)d_in[18];
    const float* outW= (const float*)d_in[19]; const float* outb= (const float*)d_in[20];
    const int* src  = (const int*)d_in[21];
    const int* dst  = (const int*)d_in[22];
    const int* nids = (const int*)d_in[23];

    const int N = in_sizes[2] / HD;
    const int E = in_sizes[1];
    const int U = in_sizes[23];
    const int C = in_sizes[20];
    const int NP = (N + 127) & ~127;    // row-padded (>= any 32-row tile end)
    const int NB1K = (N + 1023) / 1024; // scan blocks
    const int NR = (N + RSIZE - 1) / RSIZE;
    const int NPAD = NR * RSIZE;
    int NEC = 32;
    {   // keep per-chunk counts < 65536 for packed ushort ranks
        int minc = (E + 65535) / 65536;
        if (NEC < minc) NEC = minc;
    }
    const int EC = (((E + NEC - 1) / NEC) + 3) & ~3;  // multiple of 4 for int4
    const int NHIST = NR * NEC;
    const int NPREP = (N * (HD / 8) + 1023) / 1024;
    const int NGRU = (N + 31) / 32;

    float* out  = (float*)d_out;
    float* pred = out;          // [C]
    float* hout = out + C;      // [N,H]

    // workspace layout (16B-aligned chunks)
    char* p = (char*)d_ws;
    auto alloc = [&](size_t bytes) { char* r = p; p += (bytes + 15) & ~(size_t)15; return r; };
    float* dinv   = (float*)alloc((size_t)N * 4);
    float* partials = (float*)alloc((size_t)POOLB * HD * 4);
    int*   counts = (int*)alloc((size_t)N * 4);
    int*   row_ptr= (int*)alloc((size_t)(N + 1) * 4);
    int2*  es     = (int2*)alloc((size_t)E * 8);
    int*   bsums  = (int*)alloc((size_t)1024 * 4);
    int*   pc     = (int*)alloc((size_t)NEC * NPAD * 4);
    float* pw     = (float*)alloc((size_t)NEC * NPAD * 4);
    ushort* nfb   = (ushort*)alloc((size_t)NP * HD * 2);
    ushort* h0b   = (ushort*)alloc((size_t)NP * HD * 2);
    ushort* aggb  = (ushort*)alloc((size_t)NP * HD * 2);
    ushort* BT    = (ushort*)alloc((size_t)3 * 128 * 256 * 2);
    float* lb2    = (float*)alloc(384 * 4);

    front_kernel<<<NHIST + NPREP + 96 + 3, 1024, 0, stream>>>(
        dst, edge_w, pc, pw, NPAD, NR, EC, E, NHIST,
        node_feat, h0, nfb, h0b, N, NPREP,
        Wz, Wr, Wh, lzW, lrW, lhW, bz, br, bh, lzb, lrb, lhb, BT, lb2);
    reduce_scanpart_kernel<<<NB1K, 256, 0, stream>>>(pc, pw, counts, dinv,
                                                     bsums, NPAD, NEC, N);
    scanfinal_colscan_kernel<<<NB1K, 256, 0, stream>>>(counts, bsums, row_ptr,
                                                       pc, NPAD, NEC, NB1K, N);
    fill2d_kernel<<<NEC * NR, 1024, 0, stream>>>(src, dst, edge_w, dinv, pc,
                                                 es, NPAD, NR, EC, E);
    agg_feat_kernel<<<(N + 3) / 4, 256, 0, stream>>>(
        (const uint2*)nfb, dinv, row_ptr, es, (uint2*)aggb, N);
    gru_fused_kernel<<<NGRU, 256, 0, stream>>>(aggb, h0b, BT, lb2, hout, N);
    pool_partial_kernel<<<POOLB, 128, 0, stream>>>(hout, nids, partials, U);
    decoder_kernel<<<1, 128, 0, stream>>>(partials, 1.0f / (float)U,
                                          linW, linb, dnW, dnb, outW, outb, pred, C);
}

// Round 28
// 197.784 us; speedup vs baseline: 1.0219x; 1.0219x over previous
//
#include <hip/hip_runtime.h>
#include <math.h>

// TGCN (R26-best, 198us): bf16 feature-space GCN aggregation (fp32 accum,
// uint2 gathers) -> fused GRU (merged Z+R, hq in-place, 4 waves, 64-row
// tiles, depth-1 B prefetch, bf16 h0b staging). CSR via ZERO global atomics.
// NEC=32. front: 1024 threads. 8 dispatches.

#define HD 128
#define RBITS 13
#define RSIZE 8192          // nodes per histogram/fill range
#define POOLB 512           // pool partial blocks

typedef __attribute__((ext_vector_type(8))) short short8;
typedef __attribute__((ext_vector_type(4))) float f32x4;

__device__ __forceinline__ ushort f2bf(float f) {
    union { float f; unsigned u; } v; v.f = f;
    unsigned r = (v.u + 0x7FFFu + ((v.u >> 16) & 1u)) >> 16;
    return (ushort)r;
}
__device__ __forceinline__ float bf2f(ushort h) {
    union { unsigned u; float f; } v; v.u = ((unsigned)h) << 16;
    return v.f;
}
__device__ __forceinline__ float bflo(unsigned u) {
    union { unsigned u; float f; } v; v.u = u << 16; return v.f;
}
__device__ __forceinline__ float bfhi(unsigned u) {
    union { unsigned u; float f; } v; v.u = u & 0xFFFF0000u; return v.f;
}
__device__ __forceinline__ float fast_sigmoid(float x) {
    return 1.0f / (1.0f + __expf(-x));
}
__device__ __forceinline__ float fast_tanh(float x) {
    float e = __expf(-2.0f * fabsf(x));
    float m = (1.0f - e) / (1.0f + e);
    return copysignf(m, x);
}

// FRONT: block-partitioned fat kernel, 1024 threads.
__global__ __launch_bounds__(1024) void front_kernel(
        const int* __restrict__ dst, const float* __restrict__ w,
        int* __restrict__ pc, float* __restrict__ pw,
        int NPAD, int NR, int EC, int E, int NHIST,
        const float* __restrict__ nf, const float* __restrict__ h0,
        ushort* __restrict__ nfb, ushort* __restrict__ h0b, int n, int NPREP,
        const float* __restrict__ Wz, const float* __restrict__ Wr,
        const float* __restrict__ Wh,
        const float* __restrict__ lzW, const float* __restrict__ lrW,
        const float* __restrict__ lhW,
        const float* __restrict__ bz, const float* __restrict__ br,
        const float* __restrict__ bh,
        const float* __restrict__ lzb, const float* __restrict__ lrb,
        const float* __restrict__ lhb,
        ushort* __restrict__ BT, float* __restrict__ lb2) {
    __shared__ int lc[RSIZE];
    __shared__ float lw[RSIZE];
    int b = blockIdx.x;
    int t = threadIdx.x;
    if (b < NHIST) {
        int r = b % NR;
        int c = b / NR;
        for (int k = t; k < RSIZE; k += 1024) { lc[k] = 0; lw[k] = 0.0f; }
        __syncthreads();
        int base = c * EC;              // EC multiple of 4 -> 16B aligned
        int end = min(base + EC, E);
        int rbase = r << RBITS;
        for (int eb = base + t * 4; eb < end; eb += 4096) {
            if (eb + 3 < end) {
                int4 d4 = *(const int4*)(dst + eb);
                if ((d4.x >> RBITS) == r) {
                    int dl = d4.x - rbase;
                    atomicAdd(&lc[dl], 1); atomicAdd(&lw[dl], w[eb]);
                }
                if ((d4.y >> RBITS) == r) {
                    int dl = d4.y - rbase;
                    atomicAdd(&lc[dl], 1); atomicAdd(&lw[dl], w[eb + 1]);
                }
                if ((d4.z >> RBITS) == r) {
                    int dl = d4.z - rbase;
                    atomicAdd(&lc[dl], 1); atomicAdd(&lw[dl], w[eb + 2]);
                }
                if ((d4.w >> RBITS) == r) {
                    int dl = d4.w - rbase;
                    atomicAdd(&lc[dl], 1); atomicAdd(&lw[dl], w[eb + 3]);
                }
            } else {
                for (int u = 0; u < 4; ++u) {
                    int e = eb + u;
                    if (e < end) {
                        int d = dst[e];
                        if ((d >> RBITS) == r) {
                            int dl = d - rbase;
                            atomicAdd(&lc[dl], 1); atomicAdd(&lw[dl], w[e]);
                        }
                    }
                }
            }
        }
        __syncthreads();
        size_t o = (size_t)c * NPAD + (r << RBITS);
        for (int k = t; k < RSIZE; k += 1024) {
            pc[o + k] = lc[k];
            pw[o + k] = lw[k];
        }
    } else if (b < NHIST + NPREP) {
        int idx = (b - NHIST) * 1024 + t;
        int total8 = n * (HD / 8);
        if (idx < total8) {
            const float4* p = (const float4*)(nf + (size_t)idx * 8);
            float4 x = p[0], y = p[1];
            short8 o;
            o[0] = (short)f2bf(x.x); o[1] = (short)f2bf(x.y);
            o[2] = (short)f2bf(x.z); o[3] = (short)f2bf(x.w);
            o[4] = (short)f2bf(y.x); o[5] = (short)f2bf(y.y);
            o[6] = (short)f2bf(y.z); o[7] = (short)f2bf(y.w);
            *(short8*)(nfb + (size_t)idx * 8) = o;
            const float4* q = (const float4*)(h0 + (size_t)idx * 8);
            float4 a = q[0], bq = q[1];
            short8 o2;
            o2[0] = (short)f2bf(a.x); o2[1] = (short)f2bf(a.y);
            o2[2] = (short)f2bf(a.z); o2[3] = (short)f2bf(a.w);
            o2[4] = (short)f2bf(bq.x); o2[5] = (short)f2bf(bq.y);
            o2[6] = (short)f2bf(bq.z); o2[7] = (short)f2bf(bq.w);
            *(short8*)(h0b + (size_t)idx * 8) = o2;
        }
    } else if (b < NHIST + NPREP + 96) {
        if (t < 256) {
            int f = b - NHIST - NPREP;
            int g = f >> 5, kt = f & 31;
            const float* W  = (g == 0) ? Wz  : (g == 1) ? Wr  : Wh;
            const float* lW = (g == 0) ? lzW : (g == 1) ? lrW : lhW;
            int j = t & 127, kh = t >> 7;
            int k0 = kt * 4 + kh * 2;
            float m0 = 0.f, m1 = 0.f;
            for (int mm = 0; mm < 128; ++mm) {
                float lv = lW[mm * 128 + j];
                m0 += W[(k0 + 0) * 128 + mm] * lv;
                m1 += W[(k0 + 1) * 128 + mm] * lv;
            }
            ushort* dstc = BT + ((size_t)g * 128 + j) * 256;
            dstc[k0 + 0] = f2bf(m0);
            dstc[k0 + 1] = f2bf(m1);
#pragma unroll
            for (int u = 0; u < 2; ++u) {
                int mm = k0 + u;
                dstc[128 + mm] = f2bf(lW[(128 + mm) * 128 + j]);
            }
        }
    } else {
        int g = b - NHIST - NPREP - 96;
        if (t < 128) {
            const float* lW = (g == 0) ? lzW : (g == 1) ? lrW : lhW;
            const float* bg = (g == 0) ? bz  : (g == 1) ? br  : bh;
            const float* lb = (g == 0) ? lzb : (g == 1) ? lrb : lhb;
            int j = t;
            float s = lb[j];
            for (int mm = 0; mm < 128; ++mm) s += bg[mm] * lW[mm * 128 + j];
            lb2[g * 128 + j] = s;
        }
    }
}

// reduce_hist + scan_partial
__global__ __launch_bounds__(256) void reduce_scanpart_kernel(
        const int* __restrict__ pc, const float* __restrict__ pw,
        int* __restrict__ counts, float* __restrict__ dinv,
        int* __restrict__ bsums, int NPAD, int NEC, int N) {
    __shared__ int ws[4];
    int b = blockIdx.x, t = threadIdx.x;
    int i = b * 1024 + t * 4;
    int c0 = 0, c1 = 0, c2 = 0, c3 = 0;
    float d0 = 1.f, d1 = 1.f, d2 = 1.f, d3 = 1.f;
    for (int c = 0; c < NEC; ++c) {
        size_t base = (size_t)c * NPAD + i;
        int4 pcv = *(const int4*)(pc + base);
        float4 pwv = *(const float4*)(pw + base);
        c0 += pcv.x; c1 += pcv.y; c2 += pcv.z; c3 += pcv.w;
        d0 += pwv.x; d1 += pwv.y; d2 += pwv.z; d3 += pwv.w;
    }
    if (i + 3 < N) {
        int4 cv; cv.x = c0; cv.y = c1; cv.z = c2; cv.w = c3;
        *(int4*)(counts + i) = cv;
        float4 dv;
        dv.x = rsqrtf(d0); dv.y = rsqrtf(d1);
        dv.z = rsqrtf(d2); dv.w = rsqrtf(d3);
        *(float4*)(dinv + i) = dv;
    } else {
        if (i < N)     { counts[i] = c0;     dinv[i] = rsqrtf(d0); }
        if (i + 1 < N) { counts[i + 1] = c1; dinv[i + 1] = rsqrtf(d1); }
        if (i + 2 < N) { counts[i + 2] = c2; dinv[i + 2] = rsqrtf(d2); }
        if (i + 3 < N) { counts[i + 3] = c3; dinv[i + 3] = rsqrtf(d3); }
    }
    int s = 0;
    if (i < N) s += c0;
    if (i + 1 < N) s += c1;
    if (i + 2 < N) s += c2;
    if (i + 3 < N) s += c3;
    for (int off = 1; off < 64; off <<= 1) s += __shfl_xor(s, off, 64);
    if ((t & 63) == 0) ws[t >> 6] = s;
    __syncthreads();
    if (t == 0) bsums[b] = ws[0] + ws[1] + ws[2] + ws[3];
}

// scan_bsums + scan_final + col_scan
__global__ __launch_bounds__(256) void scanfinal_colscan_kernel(
        const int* __restrict__ counts, const int* __restrict__ bsums,
        int* __restrict__ row_ptr, int* __restrict__ pc,
        int NPAD, int NEC, int NB, int n) {
    __shared__ int ws[4];
    __shared__ int sb[64];
    __shared__ int stot;
    int b = blockIdx.x, t = threadIdx.x;
    if (t < 64) {
        int v = (t < NB) ? bsums[t] : 0;
        int x = v;
        for (int off = 1; off < 64; off <<= 1) {
            int y = __shfl_up(x, off, 64);
            if (t >= off) x += y;
        }
        sb[t] = x - v;
        if (t == NB - 1) stot = x;
    }
    __syncthreads();
    int base = sb[b];
    int idx = b * 1024 + t * 4;
    int4 v = {0, 0, 0, 0};
    if (idx + 3 < n) v = *(const int4*)(counts + idx);
    else {
        if (idx < n) v.x = counts[idx];
        if (idx + 1 < n) v.y = counts[idx + 1];
        if (idx + 2 < n) v.z = counts[idx + 2];
        if (idx + 3 < n) v.w = counts[idx + 3];
    }
    int s = v.x + v.y + v.z + v.w;
    int lane = t & 63, wid = t >> 6;
    int x = s;
    for (int off = 1; off < 64; off <<= 1) {
        int y = __shfl_up(x, off, 64);
        if (lane >= off) x += y;
    }
    if (lane == 63) ws[wid] = x;
    __syncthreads();
    int woff = 0;
    for (int wv = 0; wv < wid; ++wv) woff += ws[wv];
    int run = base + woff + x - s;
    int4 rp;
    rp.x = run; rp.y = run + v.x; rp.z = rp.y + v.y; rp.w = rp.z + v.z;
    if (idx + 3 < n) {
        *(int4*)(row_ptr + idx) = rp;
    } else {
        if (idx < n) row_ptr[idx] = rp.x;
        if (idx + 1 < n) row_ptr[idx + 1] = rp.y;
        if (idx + 2 < n) row_ptr[idx + 2] = rp.z;
        if (idx + 3 < n) row_ptr[idx + 3] = rp.w;
    }
    if (b == 0 && t == 0) row_ptr[n] = stot;
    int4 run4 = rp;
    for (int c = 0; c < NEC; ++c) {
        size_t ba = (size_t)c * NPAD + idx;
        int4 pv = *(const int4*)(pc + ba);
        *(int4*)(pc + ba) = run4;
        run4.x += pv.x; run4.y += pv.y; run4.z += pv.z; run4.w += pv.w;
    }
}

// fill: block (c,r); pco range-slice preloaded into LDS; packed ushort ranks;
// 1024 threads.
__global__ __launch_bounds__(1024) void fill2d_kernel(
        const int* __restrict__ src, const int* __restrict__ dst,
        const float* __restrict__ w, const float* __restrict__ dinv,
        const int* __restrict__ pc, int2* __restrict__ es,
        int NPAD, int NR, int EC, int E) {
    __shared__ int po[RSIZE];
    __shared__ unsigned pk[RSIZE / 2];
    int r = blockIdx.x % NR;
    int c = blockIdx.x / NR;
    int t = threadIdx.x;
    const int* __restrict__ pco = pc + (size_t)c * NPAD + (r << RBITS);
    for (int b = t; b < RSIZE / 2; b += 1024) pk[b] = 0u;
    for (int b = t; b < RSIZE; b += 1024) po[b] = pco[b];
    __syncthreads();
    int base = c * EC;
    int end = min(base + EC, E);
    int rbase = r << RBITS;
    for (int e = base + t; e < end; e += 1024) {
        int d = dst[e];
        if ((d >> RBITS) == r) {
            int dl = d - rbase;
            unsigned sh = (dl & 1) * 16;
            unsigned old = atomicAdd(&pk[dl >> 1], 1u << sh);
            int rank = (int)((old >> sh) & 0xFFFFu);
            int pos = po[dl] + rank;
            int s = src[e];
            float nv = dinv[s] * w[e];
            int2 ev;
            ev.x = s;
            ev.y = __float_as_int(nv);
            es[pos] = ev;
        }
    }
}

// agg: ONE node per wave; half-waves take alternating 8-edge batches; uint2.
__global__ __launch_bounds__(256) void agg_feat_kernel(
        const uint2* __restrict__ nfb2, const float* __restrict__ dinv,
        const int* __restrict__ row_ptr, const int2* __restrict__ es,
        uint2* __restrict__ aggb2, int n) {
    int lane = threadIdx.x & 63;
    int wv = threadIdx.x >> 6;
    int i = blockIdx.x * 4 + wv;
    if (i >= n) return;
    int sub = lane & 31;
    int half = lane >> 5;
    float dA = dinv[i];
    float a0 = 0.f, a1 = 0.f, a2 = 0.f, a3 = 0.f;
    int e0 = row_ptr[i], e1 = row_ptr[i + 1];
    int iters = (e1 - e0 + 15) >> 4;

    int2 zed; zed.x = 0; zed.y = 0;
    int e = e0 + half * 8;
    int2 buf[8];
#pragma unroll
    for (int u = 0; u < 8; ++u) {
        int ee = e + u;
        buf[u] = (ee < e1) ? es[ee] : zed;
    }
    for (int it = 0; it < iters; ++it) {
        uint2 v[8]; float w[8];
#pragma unroll
        for (int u = 0; u < 8; ++u) {
            v[u] = nfb2[(size_t)buf[u].x * 32 + sub];
            w[u] = __int_as_float(buf[u].y);
        }
        int en = e + 16;
#pragma unroll
        for (int u = 0; u < 8; ++u) {
            int ee = en + u;
            buf[u] = (it + 1 < iters && ee < e1) ? es[ee] : zed;
        }
#pragma unroll
        for (int u = 0; u < 8; ++u) {
            a0 += w[u] * bflo(v[u].x);
            a1 += w[u] * bfhi(v[u].x);
            a2 += w[u] * bflo(v[u].y);
            a3 += w[u] * bfhi(v[u].y);
        }
        e = en;
    }
    a0 += __shfl_xor(a0, 32, 64);
    a1 += __shfl_xor(a1, 32, 64);
    a2 += __shfl_xor(a2, 32, 64);
    a3 += __shfl_xor(a3, 32, 64);
    if (half == 0) {
        uint2 self = nfb2[(size_t)i * 32 + sub];
        float f0 = dA * (dA * bflo(self.x) + a0);
        float f1 = dA * (dA * bfhi(self.x) + a1);
        float f2 = dA * (dA * bflo(self.y) + a2);
        float f3 = dA * (dA * bfhi(self.y) + a3);
        uint2 o;
        o.x = (unsigned)f2bf(f0) | ((unsigned)f2bf(f1) << 16);
        o.y = (unsigned)f2bf(f2) | ((unsigned)f2bf(f3) << 16);
        aggb2[(size_t)i * 32 + sub] = o;
    }
}

// Fused GRU (R15-best): 64-row tile, 4 waves, merged Z+R, hq in-place over
// Ah0, bf16 h0b staging, depth-1 B prefetch.
#define BADDR(g, cf, ks) (BT + (size_t)((g) * 128 + c0 + (cf) * 16 + rlo) * 256 \
                          + (ks) * 32 + koff)
__global__ __launch_bounds__(256) void gru_fused_kernel(
        const ushort* __restrict__ aggb, const ushort* __restrict__ h0b,
        const ushort* __restrict__ BT, const float* __restrict__ lb2,
        float* __restrict__ hout, int n) {
    __shared__ ushort Aag[64][136];
    __shared__ ushort Ah0[64][136];
    int t = threadIdx.x;
    int i0 = blockIdx.x * 64;

    int w = t >> 6, lane = t & 63;
    int rlo = lane & 15, koff = (lane >> 4) * 8, rbase = (lane >> 4) * 4;
    int c0 = w * 32;

    short8 bz0 = *(const short8*)BADDR(0, 0, 0);
    short8 bz1 = *(const short8*)BADDR(0, 1, 0);
    short8 br0 = *(const short8*)BADDR(1, 0, 0);
    short8 br1 = *(const short8*)BADDR(1, 1, 0);

    for (int c = t; c < 1024; c += 256) {
        int row = c >> 4, c8 = c & 15;
        size_t gp = (size_t)(i0 + row) * HD + c8 * 8;
        *(short8*)&Aag[row][c8 * 8] = *(const short8*)(aggb + gp);
        *(short8*)&Ah0[row][c8 * 8] = *(const short8*)(h0b + gp);
    }
    __syncthreads();

    const f32x4 zero4 = {0.f, 0.f, 0.f, 0.f};
    f32x4 accz[4][2], accr[4][2];
#pragma unroll
    for (int rf = 0; rf < 4; ++rf) {
        accz[rf][0] = zero4; accz[rf][1] = zero4;
        accr[rf][0] = zero4; accr[rf][1] = zero4;
    }

#pragma unroll
    for (int ks = 0; ks < 8; ++ks) {
        short8 nz0, nz1, nr0, nr1;
        if (ks < 7) {
            nz0 = *(const short8*)BADDR(0, 0, ks + 1);
            nz1 = *(const short8*)BADDR(0, 1, ks + 1);
            nr0 = *(const short8*)BADDR(1, 0, ks + 1);
            nr1 = *(const short8*)BADDR(1, 1, ks + 1);
        }
#pragma unroll
        for (int rf = 0; rf < 4; ++rf) {
            short8 af = (ks < 4)
                ? *(const short8*)&Aag[rf * 16 + rlo][ks * 32 + koff]
                : *(const short8*)&Ah0[rf * 16 + rlo][(ks - 4) * 32 + koff];
            accz[rf][0] = __builtin_amdgcn_mfma_f32_16x16x32_bf16(af, bz0, accz[rf][0], 0, 0, 0);
            accz[rf][1] = __builtin_amdgcn_mfma_f32_16x16x32_bf16(af, bz1, accz[rf][1], 0, 0, 0);
            accr[rf][0] = __builtin_amdgcn_mfma_f32_16x16x32_bf16(af, br0, accr[rf][0], 0, 0, 0);
            accr[rf][1] = __builtin_amdgcn_mfma_f32_16x16x32_bf16(af, br1, accr[rf][1], 0, 0, 0);
        }
        if (ks < 7) { bz0 = nz0; bz1 = nz1; br0 = nr0; br1 = nr1; }
    }

    float zv[4][2][4], hv[4][2][4];
#pragma unroll
    for (int rf = 0; rf < 4; ++rf)
#pragma unroll
        for (int cf = 0; cf < 2; ++cf) {
            int lc = c0 + cf * 16 + rlo;
            float bvz = lb2[lc];
#pragma unroll
            for (int i = 0; i < 4; ++i) {
                int row = rf * 16 + rbase + i;
                zv[rf][cf][i] = fast_sigmoid(accz[rf][cf][i] + bvz);
                hv[rf][cf][i] = bf2f(Ah0[row][lc]);
            }
        }
    __syncthreads();

#pragma unroll
    for (int rf = 0; rf < 4; ++rf)
#pragma unroll
        for (int cf = 0; cf < 2; ++cf) {
            int lc = c0 + cf * 16 + rlo;
            float bvr = lb2[128 + lc];
#pragma unroll
            for (int i = 0; i < 4; ++i) {
                int row = rf * 16 + rbase + i;
                float r = fast_sigmoid(accr[rf][cf][i] + bvr);
                Ah0[row][lc] = f2bf(r * hv[rf][cf][i]);
            }
        }
    short8 bh0 = *(const short8*)BADDR(2, 0, 0);
    short8 bh1 = *(const short8*)BADDR(2, 1, 0);
    __syncthreads();

    f32x4 acch[4][2];
#pragma unroll
    for (int rf = 0; rf < 4; ++rf) { acch[rf][0] = zero4; acch[rf][1] = zero4; }
#pragma unroll
    for (int ks = 0; ks < 8; ++ks) {
        short8 nh0, nh1;
        if (ks < 7) {
            nh0 = *(const short8*)BADDR(2, 0, ks + 1);
            nh1 = *(const short8*)BADDR(2, 1, ks + 1);
        }
#pragma unroll
        for (int rf = 0; rf < 4; ++rf) {
            short8 af = (ks < 4)
                ? *(const short8*)&Aag[rf * 16 + rlo][ks * 32 + koff]
                : *(const short8*)&Ah0[rf * 16 + rlo][(ks - 4) * 32 + koff];
            acch[rf][0] = __builtin_amdgcn_mfma_f32_16x16x32_bf16(af, bh0, acch[rf][0], 0, 0, 0);
            acch[rf][1] = __builtin_amdgcn_mfma_f32_16x16x32_bf16(af, bh1, acch[rf][1], 0, 0, 0);
        }
        if (ks < 7) { bh0 = nh0; bh1 = nh1; }
    }
#pragma unroll
    for (int rf = 0; rf < 4; ++rf)
#pragma unroll
        for (int cf = 0; cf < 2; ++cf) {
            int lc = c0 + cf * 16 + rlo;
            float bv = lb2[256 + lc];
#pragma unroll
            for (int i = 0; i < 4; ++i) {
                int row = rf * 16 + rbase + i;
                int grow = i0 + row;
                if (grow < n) {
                    float ht = fast_tanh(acch[rf][cf][i] + bv);
                    float z = zv[rf][cf][i];
                    hout[(size_t)grow * HD + lc] = z * hv[rf][cf][i] + (1.0f - z) * ht;
                }
            }
        }
}

// pool: per-block partials, NO atomics.
__global__ __launch_bounds__(128) void pool_partial_kernel(
        const float* __restrict__ hout, const int* __restrict__ nids,
        float* __restrict__ partials, int U) {
    int t = threadIdx.x;
    float pa = 0.0f;
    for (int u = blockIdx.x; u < U; u += gridDim.x) {
        int nid = nids[u];
        pa += fmaxf(hout[(size_t)nid * HD + t], 0.0f);
    }
    partials[(size_t)blockIdx.x * HD + t] = pa;
}

__global__ __launch_bounds__(128) void decoder_kernel(
        const float* __restrict__ partials, float invU,
        const float* __restrict__ linW, const float* __restrict__ linb,
        const float* __restrict__ dnW, const float* __restrict__ dnb,
        const float* __restrict__ outW, const float* __restrict__ outb,
        float* pred, int C) {
    __shared__ float sh[HD];
    int t = threadIdx.x;
    float s = 0.0f;
    for (int b = 0; b < POOLB; ++b) s += partials[(size_t)b * HD + t];
    sh[t] = s * invU;
    __syncthreads();
    float v = linb[t];
    for (int k = 0; k < HD; ++k) v += sh[k] * linW[k * HD + t];
    __syncthreads();
    sh[t] = v;
    __syncthreads();
    float d = dnb[t];
    for (int k = 0; k < HD; ++k) d += sh[k] * dnW[k * HD + t];
    d = fmaxf(d, 0.0f);
    __syncthreads();
    sh[t] = d;
    __syncthreads();
    if (t < C) {
        float p = outb[t];
        for (int k = 0; k < HD; ++k) p += sh[k] * outW[k * C + t];
        pred[t] = 1.0f / (1.0f + expf(-p));
    }
}

extern "C" void kernel_launch(void* const* d_in, const int* in_sizes, int n_in,
                              void* d_out, int out_size, void* d_ws, size_t ws_size,
                              hipStream_t stream) {
    const float* node_feat = (const float*)d_in[0];
    const float* edge_w    = (const float*)d_in[1];
    const float* h0        = (const float*)d_in[2];
    const float* Wz  = (const float*)d_in[3];  const float* bz  = (const float*)d_in[4];
    const float* Wr  = (const float*)d_in[5];  const float* br  = (const float*)d_in[6];
    const float* Wh  = (const float*)d_in[7];  const float* bh  = (const float*)d_in[8];
    const float* lzW = (const float*)d_in[9];  const float* lzb = (const float*)d_in[10];
    const float* lrW = (const float*)d_in[11]; const float* lrb = (const float*)d_in[12];
    const float* lhW = (const float*)d_in[13]; const float* lhb = (const float*)d_in[14];
    const float* linW= (const float*)d_in[15]; const float* linb= (const float*)d_in[16];
    const float* dnW = (const float*)d_in[17]; const float* dnb = (const float*)d_in[18];
    const float* outW= (const float*)d_in[19]; const float* outb= (const float*)d_in[20];
    const int* src  = (const int*)d_in[21];
    const int* dst  = (const int*)d_in[22];
    const int* nids = (const int*)d_in[23];

    const int N = in_sizes[2] / HD;
    const int E = in_sizes[1];
    const int U = in_sizes[23];
    const int C = in_sizes[20];
    const int NP = (N + 127) & ~127;    // row-padded
    const int NB1K = (N + 1023) / 1024; // scan blocks
    const int NR = (N + RSIZE - 1) / RSIZE;
    const int NPAD = NR * RSIZE;
    int NEC = 32;
    {   // keep per-chunk counts < 65536 for packed ushort ranks
        int minc = (E + 65535) / 65536;
        if (NEC < minc) NEC = minc;
    }
    const int EC = (((E + NEC - 1) / NEC) + 3) & ~3;  // multiple of 4 for int4
    const int NHIST = NR * NEC;
    const int NPREP = (N * (HD / 8) + 1023) / 1024;

    float* out  = (float*)d_out;
    float* pred = out;          // [C]
    float* hout = out + C;      // [N,H]

    // workspace layout (16B-aligned chunks)
    char* p = (char*)d_ws;
    auto alloc = [&](size_t bytes) { char* r = p; p += (bytes + 15) & ~(size_t)15; return r; };
    float* dinv   = (float*)alloc((size_t)N * 4);
    float* partials = (float*)alloc((size_t)POOLB * HD * 4);
    int*   counts = (int*)alloc((size_t)N * 4);
    int*   row_ptr= (int*)alloc((size_t)(N + 1) * 4);
    int2*  es     = (int2*)alloc((size_t)E * 8);
    int*   bsums  = (int*)alloc((size_t)1024 * 4);
    int*   pc     = (int*)alloc((size_t)NEC * NPAD * 4);
    float* pw     = (float*)alloc((size_t)NEC * NPAD * 4);
    ushort* nfb   = (ushort*)alloc((size_t)NP * HD * 2);
    ushort* h0b   = (ushort*)alloc((size_t)NP * HD * 2);
    ushort* aggb  = (ushort*)alloc((size_t)NP * HD * 2);
    ushort* BT    = (ushort*)alloc((size_t)3 * 128 * 256 * 2);
    float* lb2    = (float*)alloc(384 * 4);

    front_kernel<<<NHIST + NPREP + 96 + 3, 1024, 0, stream>>>(
        dst, edge_w, pc, pw, NPAD, NR, EC, E, NHIST,
        node_feat, h0, nfb, h0b, N, NPREP,
        Wz, Wr, Wh, lzW, lrW, lhW, bz, br, bh, lzb, lrb, lhb, BT, lb2);
    reduce_scanpart_kernel<<<NB1K, 256, 0, stream>>>(pc, pw, counts, dinv,
                                                     bsums, NPAD, NEC, N);
    scanfinal_colscan_kernel<<<NB1K, 256, 0, stream>>>(counts, bsums, row_ptr,
                                                       pc, NPAD, NEC, NB1K, N);
    fill2d_kernel<<<NEC * NR, 1024, 0, stream>>>(src, dst, edge_w, dinv, pc,
                                                 es, NPAD, NR, EC, E);
    agg_feat_kernel<<<(N + 3) / 4, 256, 0, stream>>>(
        (const uint2*)nfb, dinv, row_ptr, es, (uint2*)aggb, N);
    gru_fused_kernel<<<NP / 64, 256, 0, stream>>>(aggb, h0b, BT, lb2, hout, N);
    pool_partial_kernel<<<POOLB, 128, 0, stream>>>(hout, nids, partials, U);
    decoder_kernel<<<1, 128, 0, stream>>>(partials, 1.0f / (float)U,
                                          linW, linb, dnW, dnb, outW, outb, pred, C);
}